// Round 6
// baseline (835.659 us; speedup 1.0000x reference)
//
#include <hip/hip_runtime.h>
#include <hip/hip_bf16.h>
#include <cstdint>
#include <cstddef>

#define B_ 64
#define T_ 2048
#define LDP 40     // As pad (proven round 2). Bs is UNPADDED (global_load_lds needs linear dest)

typedef unsigned short ushort_t;
typedef __attribute__((ext_vector_type(8))) short bf16x8;   // 8 bf16 (4 VGPRs)
typedef __attribute__((ext_vector_type(4))) float f32x4;    // MFMA C/D

__device__ __forceinline__ float sigmoidf_(float x){ return 1.f/(1.f+__expf(-x)); }
__device__ __forceinline__ float tanhf_(float x){
  x = fminf(fmaxf(x,-15.f),15.f);
  float e = __expf(2.f*x);
  return (e-1.f)/(e+1.f);
}

// RNE fp32->bf16 pair packed into one dword
__device__ __forceinline__ unsigned f2b_pair(float lo, float hi){
  unsigned a = __float_as_uint(lo), b = __float_as_uint(hi);
  a += 0x7FFFu + ((a>>16)&1u);
  b += 0x7FFFu + ((b>>16)&1u);
  return (a>>16) | (b & 0xFFFF0000u);
}
__device__ __forceinline__ uint4 pack8(float4 x, float4 y){
  uint4 v;
  v.x = f2b_pair(x.x, x.y);
  v.y = f2b_pair(x.z, x.w);
  v.z = f2b_pair(y.x, y.y);
  v.w = f2b_pair(y.z, y.w);
  return v;
}

// async global->LDS, 16B per lane (wave-uniform LDS base + lane*16)
__device__ __forceinline__ void gload_lds16(const ushort_t* g, ushort_t* l){
  __builtin_amdgcn_global_load_lds(
      (const __attribute__((address_space(1))) unsigned int*)g,
      (__attribute__((address_space(3))) unsigned int*)l, 16, 0, 0);
}

// rel_table[r][j] = rel_emb[r] . rel_w_ih[j] + rel_b_ih[j], r<64, j<768  (fp32)
__global__ __launch_bounds__(256)
void table_kernel(const float* __restrict__ rel_emb, const float* __restrict__ w_ih,
                  const float* __restrict__ b_ih, float* __restrict__ table)
{
  int idx = blockIdx.x*256 + threadIdx.x;   // < 64*768
  int r = idx/768, j = idx - r*768;
  const float* e = rel_emb + (size_t)r*256;
  const float* w = w_ih   + (size_t)j*256;
  float acc = 0.f;
  for(int k=0;k<256;k+=4){
    float4 ev = *(const float4*)(e+k);
    float4 wv = *(const float4*)(w+k);
    acc = fmaf(ev.x,wv.x,acc); acc = fmaf(ev.y,wv.y,acc);
    acc = fmaf(ev.z,wv.z,acc); acc = fmaf(ev.w,wv.w,acc);
  }
  table[idx] = acc + b_ih[j];
}

// convert the three 768x256 weight matrices to bf16 (row-major, K contiguous)
__global__ __launch_bounds__(256)
void wcvt_kernel(const float* __restrict__ a, const float* __restrict__ b, const float* __restrict__ c,
                 ushort_t* __restrict__ oa, ushort_t* __restrict__ ob, ushort_t* __restrict__ oc)
{
  int i = blockIdx.x*256 + threadIdx.x;     // < 3*24576
  int seg = i / 24576;
  int off = (i - seg*24576) * 8;
  const float* s; ushort_t* d;
  if(seg==0){ s=a; d=oa; } else if(seg==1){ s=b; d=ob; } else { s=c; d=oc; }
  float4 x = *(const float4*)(s+off), y = *(const float4*)(s+off+4);
  *(uint4*)(d+off) = pack8(x,y);
}

// ---------------------------------------------------------------------------
// Round-5 kernels = proven round-2 structure (128 x 192 tile, grid (M/128,4))
// with two staging changes:
//  (1) B (weights, already bf16) staged via global_load_lds into a
//      double-buffered UNPADDED Bs[2][192][32], issued one k-step early --
//      off the VALU/register path entirely; DMA rides under compute.
//      Chunk map: wave w issues 3 chunks ch=w*3..w*3+2; chunk = 16 W rows;
//      lane l -> W row (ch>>2)*256 + nb*64 + (ch&3)*16 + (l>>2),
//                16B at k-offset kk + (l&3)*8  ->  LDS Bs[pn][ch*16..+16).
//  (2) A (fp32, needs pack) keeps the register path but prefetched 2-DEEP
//      (two reg sets, k-loop unrolled x2) -- VGPRs are free inside the
//      256-granule (round-2 was 152 -> already 2 waves/SIMD).
// C/D layout (m89-verified): col = lane&15, row = (lane>>4)*4 + reg.
// ---------------------------------------------------------------------------

template<bool LEAF>
__global__ __launch_bounds__(256)
void node_mfma(const float* __restrict__ embs, const float* __restrict__ red,
               const ushort_t* __restrict__ wih, const ushort_t* __restrict__ whh,
               const float* __restrict__ b_ih, const float* __restrict__ b_hh,
               float* __restrict__ out, int t_lo, unsigned cnt, unsigned Mtot)
{
  __shared__ ushort_t As[128][LDP];
  __shared__ ushort_t Bs[2][192][32];
  const int tid  = threadIdx.x;
  const unsigned Mbase = blockIdx.x*128u;
  const int nb   = blockIdx.y;
  const int lane = tid & 63, w = tid >> 6;
  const int quad = lane >> 4, cl = lane & 15;

  const int srow = tid >> 2;
  const int g8   = (tid & 3) * 8;
  unsigned r0 = Mbase + srow;      if(r0 > Mtot-1) r0 = Mtot-1;
  unsigned r1 = Mbase + srow + 64; if(r1 > Mtot-1) r1 = Mtot-1;
  unsigned b0v = r0 / cnt, t0v = (unsigned)t_lo + (r0 - b0v*cnt);
  unsigned b1v = r1 / cnt, t1v = (unsigned)t_lo + (r1 - b1v*cnt);
  const float* x0p = embs + ((size_t)b0v*T_ + t0v)*256 + g8;
  const float* x1p = embs + ((size_t)b1v*T_ + t1v)*256 + g8;
  const float* rd0p = red + ((size_t)b0v*256 + t0v)*256 + g8;
  const float* rd1p = red + ((size_t)b1v*256 + t1v)*256 + g8;

  f32x4 acc[2][12];
  f32x4 accN2[2][4];
  const f32x4 zz = {0.f,0.f,0.f,0.f};
  #pragma unroll
  for(int i=0;i<2;i++){
    #pragma unroll
    for(int j=0;j<12;j++) acc[i][j] = zz;
    #pragma unroll
    for(int j=0;j<4;j++) accN2[i][j] = zz;
  }

  const int KSTOT = LEAF ? 256 : 512;   // pass 0: x @ wih ; pass 1: red @ whh
  float4 aR[2][4];                       // two A prefetch sets (static-indexed)

#define ALOAD(SET, KS) do{ \
    const int kk_ = (KS) & 255; \
    const float* A0_ = (LEAF || (KS) < 256) ? x0p : rd0p; \
    const float* A1_ = (LEAF || (KS) < 256) ? x1p : rd1p; \
    aR[SET][0] = *(const float4*)(A0_+kk_); aR[SET][1] = *(const float4*)(A0_+kk_+4); \
    aR[SET][2] = *(const float4*)(A1_+kk_); aR[SET][3] = *(const float4*)(A1_+kk_+4); \
  }while(0)

#define BDMA(KS, PN) do{ \
    const ushort_t* W_ = (LEAF || (KS) < 256) ? wih : whh; \
    const int kk_ = (KS) & 255; \
    const int ch0_ = w*3; \
    gload_lds16(W_ + (size_t)((ch0_>>2)*256 + nb*64 + (ch0_&3)*16 + (lane>>2))*256 + kk_ + (lane&3)*8, &Bs[PN][ch0_*16][0]); \
    const int ch1_ = w*3+1; \
    gload_lds16(W_ + (size_t)((ch1_>>2)*256 + nb*64 + (ch1_&3)*16 + (lane>>2))*256 + kk_ + (lane&3)*8, &Bs[PN][ch1_*16][0]); \
    const int ch2_ = w*3+2; \
    gload_lds16(W_ + (size_t)((ch2_>>2)*256 + nb*64 + (ch2_&3)*16 + (lane>>2))*256 + kk_ + (lane&3)*8, &Bs[PN][ch2_*16][0]); \
  }while(0)

#define COMPUTE(KS, P) do{ \
    const bool p1_ = (!LEAF) && ((KS) >= 256); \
    bf16x8 af0 = *(const bf16x8*)&As[w*32      + cl][quad*8]; \
    bf16x8 af1 = *(const bf16x8*)&As[w*32 + 16 + cl][quad*8]; \
    _Pragma("unroll") \
    for(int j=0;j<12;j++){ \
      bf16x8 bfj = *(const bf16x8*)&Bs[P][j*16 + cl][quad*8]; \
      if(j>=8 && p1_){ \
        accN2[0][j-8] = __builtin_amdgcn_mfma_f32_16x16x32_bf16(af0, bfj, accN2[0][j-8], 0,0,0); \
        accN2[1][j-8] = __builtin_amdgcn_mfma_f32_16x16x32_bf16(af1, bfj, accN2[1][j-8], 0,0,0); \
      } else { \
        acc[0][j] = __builtin_amdgcn_mfma_f32_16x16x32_bf16(af0, bfj, acc[0][j], 0,0,0); \
        acc[1][j] = __builtin_amdgcn_mfma_f32_16x16x32_bf16(af1, bfj, acc[1][j], 0,0,0); \
      } \
    } \
  }while(0)

  // prologue: DMA B(0) into Bs[0]; A sets 0/1 <- steps 0/32
  BDMA(0, 0);
  ALOAD(0, 0);
  ALOAD(1, 32);

  #pragma unroll 1
  for(int kk=0; kk<KSTOT; kk+=64){
    // substep 0: step kk (Bs[0], A set 0)
    __syncthreads();                         // readers done + drains B-DMA/loads
    *(uint4*)&As[srow   ][g8] = pack8(aR[0][0], aR[0][1]);
    *(uint4*)&As[srow+64][g8] = pack8(aR[0][2], aR[0][3]);
    __syncthreads();                         // publish As + Bs[0]
    BDMA(kk+32, 1);                          // DMA next step's B under compute
    if(kk+64 < KSTOT) ALOAD(0, kk+64);       // 2-deep A prefetch
    COMPUTE(kk, 0);
    // substep 1: step kk+32 (Bs[1], A set 1)
    __syncthreads();
    *(uint4*)&As[srow   ][g8] = pack8(aR[1][0], aR[1][1]);
    *(uint4*)&As[srow+64][g8] = pack8(aR[1][2], aR[1][3]);
    __syncthreads();
    if(kk+64 < KSTOT) BDMA(kk+64, 0);
    if(kk+96 < KSTOT) ALOAD(1, kk+96);
    COMPUTE(kk+32, 1);
  }
#undef ALOAD
#undef BDMA
#undef COMPUTE

  // epilogue: GRU combine, fp32 store (clamped duplicate rows write same value)
  float bir[4],biz[4],bin[4],bhr[4],bhz[4],bhn[4];
  #pragma unroll
  for(int c=0;c<4;c++){
    int col = nb*64 + c*16 + cl;
    bir[c]=b_ih[col]; biz[c]=b_ih[256+col]; bin[c]=b_ih[512+col];
    bhr[c]=b_hh[col]; bhz[c]=b_hh[256+col]; bhn[c]=b_hh[512+col];
  }
  #pragma unroll
  for(int i=0;i<2;i++){
    #pragma unroll
    for(int r=0;r<4;r++){
      unsigned gm = Mbase + (unsigned)(w*32 + i*16 + quad*4 + r);
      if(gm > Mtot-1) gm = Mtot-1;
      unsigned b = gm / cnt, t = (unsigned)t_lo + (gm - b*cnt);
      float* orow = out + ((size_t)b*T_ + t)*256;
      const float* rr = red + ((size_t)b*256 + t)*256;
      #pragma unroll
      for(int c=0;c<4;c++){
        int col = nb*64 + c*16 + cl;
        float gr = acc[i][c][r]   + bir[c] + bhr[c];
        float gz = acc[i][4+c][r] + biz[c] + bhz[c];
        float gni = acc[i][8+c][r] + bin[c];
        float hn  = (LEAF ? 0.f : accN2[i][c][r]) + bhn[c];
        float rg = sigmoidf_(gr);
        float zg = sigmoidf_(gz);
        float ng = tanhf_(gni + rg*hn);
        float rv = LEAF ? 0.f : rr[col];
        orow[col] = (1.f-zg)*ng + zg*rv;
      }
    }
  }
}

// msg: gates = table[rel] (gi) + h @ rel_w_hh^T + rel_b_hh; red[parent] += msg
__global__ __launch_bounds__(256)
void msg_mfma(const float* __restrict__ hbuf, const ushort_t* __restrict__ wbf,
              const float* __restrict__ b_hh, const float* __restrict__ table,
              const int* __restrict__ rels, float* __restrict__ red,
              int t_lo, unsigned cnt, unsigned Mtot)
{
  __shared__ ushort_t As[128][LDP];
  __shared__ ushort_t Bs[2][192][32];
  const int tid  = threadIdx.x;
  const unsigned Mbase = blockIdx.x*128u;
  const int nb   = blockIdx.y;
  const int lane = tid & 63, w = tid >> 6;
  const int quad = lane >> 4, cl = lane & 15;

  const int srow = tid >> 2;
  const int g8   = (tid & 3) * 8;
  unsigned r0 = Mbase + srow;      if(r0 > Mtot-1) r0 = Mtot-1;
  unsigned r1 = Mbase + srow + 64; if(r1 > Mtot-1) r1 = Mtot-1;
  unsigned b0v = r0 / cnt, t0v = (unsigned)t_lo + (r0 - b0v*cnt);
  unsigned b1v = r1 / cnt, t1v = (unsigned)t_lo + (r1 - b1v*cnt);
  const float* a0 = hbuf + ((size_t)b0v*T_ + t0v)*256 + g8;
  const float* a1 = hbuf + ((size_t)b1v*T_ + t1v)*256 + g8;

  f32x4 acc[2][12];
  const f32x4 zz = {0.f,0.f,0.f,0.f};
  #pragma unroll
  for(int i=0;i<2;i++)
    #pragma unroll
    for(int j=0;j<12;j++) acc[i][j] = zz;

  // hoist the epilogue's rels gather above the GEMM (first link of the
  // dependent chain rels -> table row -> gathers); +8 VGPR, free in granule
  int relv[2][4];
  #pragma unroll
  for(int i=0;i<2;i++)
    #pragma unroll
    for(int r=0;r<4;r++){
      unsigned gm = Mbase + (unsigned)(w*32 + i*16 + quad*4 + r);
      if(gm > Mtot-1) gm = Mtot-1;
      unsigned b = gm / cnt, t = (unsigned)t_lo + (gm - b*cnt);
      relv[i][r] = rels[(size_t)b*T_ + t];
    }

  float4 aR[2][4];

#define MALOAD(SET, KK) do{ \
    aR[SET][0] = *(const float4*)(a0+(KK)); aR[SET][1] = *(const float4*)(a0+(KK)+4); \
    aR[SET][2] = *(const float4*)(a1+(KK)); aR[SET][3] = *(const float4*)(a1+(KK)+4); \
  }while(0)

#define MBDMA(KK, PN) do{ \
    const int ch0_ = w*3; \
    gload_lds16(wbf + (size_t)((ch0_>>2)*256 + nb*64 + (ch0_&3)*16 + (lane>>2))*256 + (KK) + (lane&3)*8, &Bs[PN][ch0_*16][0]); \
    const int ch1_ = w*3+1; \
    gload_lds16(wbf + (size_t)((ch1_>>2)*256 + nb*64 + (ch1_&3)*16 + (lane>>2))*256 + (KK) + (lane&3)*8, &Bs[PN][ch1_*16][0]); \
    const int ch2_ = w*3+2; \
    gload_lds16(wbf + (size_t)((ch2_>>2)*256 + nb*64 + (ch2_&3)*16 + (lane>>2))*256 + (KK) + (lane&3)*8, &Bs[PN][ch2_*16][0]); \
  }while(0)

#define MCOMPUTE(P) do{ \
    bf16x8 af0 = *(const bf16x8*)&As[w*32      + cl][quad*8]; \
    bf16x8 af1 = *(const bf16x8*)&As[w*32 + 16 + cl][quad*8]; \
    _Pragma("unroll") \
    for(int j=0;j<12;j++){ \
      bf16x8 bfj = *(const bf16x8*)&Bs[P][j*16 + cl][quad*8]; \
      acc[0][j] = __builtin_amdgcn_mfma_f32_16x16x32_bf16(af0, bfj, acc[0][j], 0,0,0); \
      acc[1][j] = __builtin_amdgcn_mfma_f32_16x16x32_bf16(af1, bfj, acc[1][j], 0,0,0); \
    } \
  }while(0)

  MBDMA(0, 0);
  MALOAD(0, 0);
  MALOAD(1, 32);

  #pragma unroll 1
  for(int kk=0; kk<256; kk+=64){
    // substep 0: step kk (Bs[0], A set 0)
    __syncthreads();
    *(uint4*)&As[srow   ][g8] = pack8(aR[0][0], aR[0][1]);
    *(uint4*)&As[srow+64][g8] = pack8(aR[0][2], aR[0][3]);
    __syncthreads();
    MBDMA(kk+32, 1);
    if(kk+64 < 256) MALOAD(0, kk+64);
    MCOMPUTE(0);
    // substep 1: step kk+32 (Bs[1], A set 1)
    __syncthreads();
    *(uint4*)&As[srow   ][g8] = pack8(aR[1][0], aR[1][1]);
    *(uint4*)&As[srow+64][g8] = pack8(aR[1][2], aR[1][3]);
    __syncthreads();
    if(kk+64 < 256) MBDMA(kk+64, 0);
    if(kk+96 < 256) MALOAD(1, kk+96);
    MCOMPUTE(1);
  }
#undef MALOAD
#undef MBDMA
#undef MCOMPUTE

  float bhr[4],bhz[4],bhn[4];
  #pragma unroll
  for(int c=0;c<4;c++){
    int col = nb*64 + c*16 + cl;
    bhr[c]=b_hh[col]; bhz[c]=b_hh[256+col]; bhn[c]=b_hh[512+col];
  }
  #pragma unroll
  for(int i=0;i<2;i++){
    float* rp[4]; bool okr[4]; const float* tb[4]; const float* hrp[4];
    #pragma unroll
    for(int r=0;r<4;r++){
      unsigned gm = Mbase + (unsigned)(w*32 + i*16 + quad*4 + r);
      okr[r] = (gm < Mtot);
      if(gm > Mtot-1) gm = Mtot-1;
      unsigned b = gm / cnt, t = (unsigned)t_lo + (gm - b*cnt);
      tb[r]  = table + (size_t)relv[i][r]*768;
      hrp[r] = hbuf + ((size_t)b*T_ + t)*256;
      rp[r]  = red + ((size_t)b*256 + ((t-1)>>3))*256;
    }
    float mv[4][4];
    #pragma unroll
    for(int r=0;r<4;r++){
      #pragma unroll
      for(int c=0;c<4;c++){
        int col = nb*64 + c*16 + cl;
        float gr  = tb[r][col]     + acc[i][c][r]   + bhr[c];
        float gz  = tb[r][256+col] + acc[i][4+c][r] + bhz[c];
        float gnh = acc[i][8+c][r] + bhn[c];
        float rg = sigmoidf_(gr);
        float zg = sigmoidf_(gz);
        float ng = tanhf_(tb[r][512+col] + rg*gnh);
        mv[r][c] = (1.f-zg)*ng + zg*hrp[r][col];
      }
    }
    // run-merged atomics (consecutive rows usually share the parent row)
    #pragma unroll
    for(int c=0;c<4;c++){
      int col = nb*64 + c*16 + cl;
      float a = 0.f; bool any = false;
      #pragma unroll
      for(int r=0;r<4;r++){
        if(okr[r]){ a += mv[r][c]; any = true; }
        bool flush;
        if(r==3) flush = true; else flush = (rp[r+1] != rp[r]);
        if(flush){
          if(any) atomicAdd(rp[r] + col, a);
          a = 0.f; any = false;
        }
      }
    }
  }
}

extern "C" void kernel_launch(void* const* d_in, const int* in_sizes, int n_in,
                              void* d_out, int out_size, void* d_ws, size_t ws_size,
                              hipStream_t stream)
{
  const float* embs    = (const float*)d_in[0];
  const float* rel_emb = (const float*)d_in[1];
  const float* nwih    = (const float*)d_in[2];
  const float* nwhh    = (const float*)d_in[3];
  const float* nbih    = (const float*)d_in[4];
  const float* nbhh    = (const float*)d_in[5];
  const float* rwih    = (const float*)d_in[6];
  const float* rwhh    = (const float*)d_in[7];
  const float* rbih    = (const float*)d_in[8];
  const float* rbhh    = (const float*)d_in[9];
  const int*   rels    = (const int*)d_in[11];
  float* out = (float*)d_out;

  float* red   = (float*)d_ws;              // [64][256][256] fp32 mailbox
  float* table = red + (size_t)4194304;     // [64][768] fp32
  ushort_t* wih_bf  = (ushort_t*)(table + 49152);
  ushort_t* whh_bf  = wih_bf + 196608;
  ushort_t* rwhh_bf = whh_bf + 196608;

  hipMemsetAsync(red, 0, (size_t)4194304*4, stream);
  table_kernel<<<dim3(192), 256, 0, stream>>>(rel_emb, rwih, rbih, table);
  wcvt_kernel<<<dim3(288), 256, 0, stream>>>(nwih, nwhh, rwhh, wih_bf, whh_bf, rwhh_bf);

  // topological levels of the deterministic 8-ary heap over 2048 nodes
  const int      tlo[5] = {256, 32, 4, 1, 0};
  const unsigned cntv[5]= {1792, 224, 28, 3, 1};
  const unsigned Mv[5]  = {114688, 14336, 1792, 192, 64};

  for(int L=0; L<5; L++){
    dim3 g((Mv[L]+127)/128, 4);
    if(L==0)
      node_mfma<true ><<<g, 256, 0, stream>>>(embs, red, wih_bf, whh_bf, nbih, nbhh, out, tlo[L], cntv[L], Mv[L]);
    else
      node_mfma<false><<<g, 256, 0, stream>>>(embs, red, wih_bf, whh_bf, nbih, nbhh, out, tlo[L], cntv[L], Mv[L]);
    if(L < 4)
      msg_mfma<<<g, 256, 0, stream>>>(out, rwhh_bf, rbhh, table, rels, red, tlo[L], cntv[L], Mv[L]);
  }
}